// Round 6
// baseline (1132.573 us; speedup 1.0000x reference)
//
#include <hip/hip_runtime.h>
#include <hip/hip_bf16.h>
#include <math.h>

#define BB 4
#define EE 8192
#define NN 1024
#define FF 512
#define DD 512
#define ALPHA 0.2f
#define SLOTS 64
#define NEX 8192              // extract blocks (4 edges each)
#define NGEMM 256
#define NP 1024
#define NOUT 1024
#define DONE_TARGET (NEX + NGEMM + NP)  // 9472

typedef __attribute__((ext_vector_type(8))) short short8;
typedef __attribute__((ext_vector_type(4))) float f32x4;

static __device__ __forceinline__ float leaky(float x) { return x > 0.f ? x : ALPHA * x; }

static __device__ __forceinline__ float wave_sum(float v) {
#pragma unroll
    for (int m = 32; m >= 1; m >>= 1) v += __shfl_xor(v, m);
    return v;
}
static __device__ __forceinline__ float wave_max(float v) {
#pragma unroll
    for (int m = 32; m >= 1; m >>= 1) v = fmaxf(v, __shfl_xor(v, m));
    return v;
}
static __device__ __forceinline__ float dot4(float4 a, float4 b) {
    return a.x * b.x + a.y * b.y + a.z * b.z + a.w * b.w;
}
static __device__ __forceinline__ short8 cvt8(float4 a, float4 b) {
    __hip_bfloat16 t[8];
    t[0] = __float2bfloat16(a.x); t[1] = __float2bfloat16(a.y);
    t[2] = __float2bfloat16(a.z); t[3] = __float2bfloat16(a.w);
    t[4] = __float2bfloat16(b.x); t[5] = __float2bfloat16(b.y);
    t[6] = __float2bfloat16(b.z); t[7] = __float2bfloat16(b.w);
    return *(short8*)t;
}
static __device__ __forceinline__ float b2f(short s) {
    unsigned u = ((unsigned)(unsigned short)s) << 16;
    float f;
    __builtin_memcpy(&f, &u, 4);
    return f;
}
static __device__ __forceinline__ short f2b(float f) {
    __hip_bfloat16 h = __float2bfloat16(f);
    short s;
    __builtin_memcpy(&s, &h, 2);
    return s;
}
// locate nonzero within a 3-chunk (768-elem) window; -1 if absent (wave-uniform result)
static __device__ __forceinline__ int find3(uint4 a, uint4 b, uint4 c, int lane) {
    unsigned na = a.x | a.y | a.z | a.w;
    unsigned nb = b.x | b.y | b.z | b.w;
    unsigned nc = c.x | c.y | c.z | c.w;
    int il = -1;
    if (na) il = lane * 4 + (a.x ? 0 : (a.y ? 1 : (a.z ? 2 : 3)));
    else if (nb) il = 256 + lane * 4 + (b.x ? 0 : (b.y ? 1 : (b.z ? 2 : 3)));
    else if (nc) il = 512 + lane * 4 + (c.x ? 0 : (c.y ? 1 : (c.z ? 2 : 3)));
    unsigned long long m = __ballot(il >= 0);
    if (!m) return -1;
    return __shfl(il, (int)__ffsll(m) - 1);
}
// locate within a single 256-elem chunk; -1 if absent (wave-uniform result)
static __device__ __forceinline__ int find1(uint4 v, int lane) {
    unsigned nz = v.x | v.y | v.z | v.w;
    unsigned long long m = __ballot(nz != 0u);
    if (!m) return -1;
    int il = lane * 4 + (v.x ? 0 : (v.y ? 1 : (v.z ? 2 : 3)));
    return __shfl(il, (int)__ffsll(m) - 1);
}

// ---------------- K1 (prep): w transpose->bf16, wa = w@a, zero cur+done ----------------
__global__ __launch_bounds__(256) void k_prep(const float* __restrict__ w,
                                              const float* __restrict__ attn,
                                              __hip_bfloat16* __restrict__ BT,
                                              float* __restrict__ wa1, float* __restrict__ wa2,
                                              int* __restrict__ cur, int* __restrict__ done) {
    int bx = blockIdx.x;
    if (bx < 64) {
        __shared__ float tile[64][65];
        int tk = bx >> 3, tn = bx & 7;
        int k0 = tk * 64, n0 = tn * 64;
#pragma unroll
        for (int it = 0; it < 16; ++it) {
            int id = it * 256 + threadIdx.x;
            int r = id >> 6, c = id & 63;
            tile[r][c] = w[(size_t)(k0 + r) * DD + n0 + c];
        }
        __syncthreads();
#pragma unroll
        for (int it = 0; it < 16; ++it) {
            int id = it * 256 + threadIdx.x;
            int r = id >> 6, c = id & 63;
            BT[(size_t)(n0 + r) * FF + k0 + c] = __float2bfloat16(tile[c][r]);
        }
        return;
    }
    if (bx < 192) {
        int f = (bx - 64) * 4 + (threadIdx.x >> 6);
        int lane = threadIdx.x & 63;
        const float4* wr = (const float4*)(w + (size_t)f * DD);
        const float4* a1p = (const float4*)attn;
        const float4* a2p = (const float4*)(attn + DD);
        float4 wv0 = wr[lane], wv1 = wr[64 + lane];
        float s1 = dot4(wv0, a1p[lane]) + dot4(wv1, a1p[64 + lane]);
        float s2 = dot4(wv0, a2p[lane]) + dot4(wv1, a2p[64 + lane]);
        s1 = wave_sum(s1);
        s2 = wave_sum(s2);
        if (lane == 0) {
            wa1[f] = s1;
            wa2[f] = s2;
        }
        return;
    }
    int4* cp = (int4*)cur;
    int4 z4 = {0, 0, 0, 0};
#pragma unroll
    for (int j = 0; j < 4; j++) cp[threadIdx.x * 4 + j] = z4;
    if (threadIdx.x == 0) done[0] = 0;
}

// ---------------- K2 (mega): extract + gemm + p + (spin-gated) output, one kernel -------
#define BM 128
#define BN 64
#define BK 32
__global__ __launch_bounds__(256) void k_mega(const float* __restrict__ nodes,
                                              const __hip_bfloat16* __restrict__ BTbf,
                                              const float* __restrict__ wa1,
                                              const float* __restrict__ wa2,
                                              const float* __restrict__ C,
                                              const float* __restrict__ Nm,
                                              short* __restrict__ Z16,
                                              float* __restrict__ p1, float* __restrict__ p2,
                                              int* __restrict__ cur, int* __restrict__ sDst,
                                              int* __restrict__ done,
                                              float* __restrict__ out) {
    __shared__ short As[BM][BK + 8];
    __shared__ short Bs[BN][BK + 8];
    int bx = blockIdx.x;
    int t = threadIdx.x;
    int lane = t & 63;
    if (bx < NEX) {
        // ---- extract + scatter: one wave per edge; 3-chunk window then chunk 3 ----
        int widx = bx * 4 + (t >> 6);
        const uint4* rc = (const uint4*)(C + (size_t)widx * NN);
        const uint4* rn = (const uint4*)(Nm + (size_t)widx * NN);
        uint4 a0 = rc[lane], a1 = rc[64 + lane], a2 = rc[128 + lane];
        uint4 b0 = rn[lane], b1 = rn[64 + lane], b2 = rn[128 + lane];
        int s = find3(a0, a1, a2, lane);
        int d = find3(b0, b1, b2, lane);
        if (s < 0 || d < 0) {
            uint4 va, vb;
            if (s < 0) va = rc[192 + lane];
            if (d < 0) vb = rn[192 + lane];
            if (s < 0) {
                int r = find1(va, lane);
                if (r >= 0) s = 768 + r;
            }
            if (d < 0) {
                int r = find1(vb, lane);
                if (r >= 0) d = 768 + r;
            }
        }
        if (lane == 0) {
            int b = widx >> 13;  // EE = 8192
            int row = b * NN + s;
            int pos = atomicAdd(&cur[row], 1);
            if (pos < SLOTS) sDst[row * SLOTS + pos] = d;
        }
        __syncthreads();
        __threadfence();
        if (t == 0) __hip_atomic_fetch_add(done, 1, __ATOMIC_RELEASE, __HIP_MEMORY_SCOPE_AGENT);
        return;
    }
    if (bx < NEX + NGEMM) {
        // ---- GEMM: Z16 = bf16(nodes) @ BT^T ----
        int gb = bx - NEX;
        int m0 = (gb & 31) * BM;
        int n0 = (gb >> 5) * BN;
        int wid = t >> 6;
        int wm = wid & 1, wn = wid >> 1;
        f32x4 acc[4][2] = {};
        const short* Bg = (const short*)BTbf;
        for (int k0 = 0; k0 < FF; k0 += BK) {
#pragma unroll
            for (int s = 0; s < 2; s++) {
                int cid = t + s * 256;
                int r = cid >> 2, cc = cid & 3;
                const float4* ap = (const float4*)&nodes[(size_t)(m0 + r) * FF + k0 + cc * 8];
                *(short8*)&As[r][cc * 8] = cvt8(ap[0], ap[1]);
            }
            {
                int r = t >> 2, cc = t & 3;
                *(short8*)&Bs[r][cc * 8] = *(const short8*)&Bg[(size_t)(n0 + r) * FF + k0 + cc * 8];
            }
            __syncthreads();
            short8 af[4];
            short8 bf[2];
#pragma unroll
            for (int m = 0; m < 4; m++)
                af[m] = *(const short8*)&As[wm * 64 + m * 16 + (lane & 15)][(lane >> 4) * 8];
#pragma unroll
            for (int n = 0; n < 2; n++)
                bf[n] = *(const short8*)&Bs[wn * 32 + n * 16 + (lane & 15)][(lane >> 4) * 8];
#pragma unroll
            for (int m = 0; m < 4; m++)
#pragma unroll
                for (int n = 0; n < 2; n++)
                    acc[m][n] = __builtin_amdgcn_mfma_f32_16x16x32_bf16(af[m], bf[n], acc[m][n], 0, 0, 0);
            __syncthreads();
        }
#pragma unroll
        for (int m = 0; m < 4; m++)
#pragma unroll
            for (int n = 0; n < 2; n++)
#pragma unroll
                for (int r = 0; r < 4; r++) {
                    int row = m0 + wm * 64 + m * 16 + (lane >> 4) * 4 + r;
                    int col = n0 + wn * 32 + n * 16 + (lane & 15);
                    Z16[(size_t)row * DD + col] = f2b(acc[m][n][r]);
                }
        __syncthreads();
        __threadfence();
        if (t == 0) __hip_atomic_fetch_add(done, 1, __ATOMIC_RELEASE, __HIP_MEMORY_SCOPE_AGENT);
        return;
    }
    if (bx < NEX + NGEMM + NP) {
        // ---- p1/p2 = nodes @ wa1/wa2 (fp32), one wave per row ----
        int rid = (bx - NEX - NGEMM) * 4 + (t >> 6);
        const float4* nr = (const float4*)(nodes + (size_t)rid * FF);
        const float4* w1p = (const float4*)wa1;
        const float4* w2p = (const float4*)wa2;
        float4 v0 = nr[lane], v1 = nr[64 + lane];
        float s1 = dot4(v0, w1p[lane]) + dot4(v1, w1p[64 + lane]);
        float s2 = dot4(v0, w2p[lane]) + dot4(v1, w2p[64 + lane]);
        s1 = wave_sum(s1);
        s2 = wave_sum(s2);
        if (lane == 0) {
            p1[rid] = s1;
            p2[rid] = s2;
        }
        __syncthreads();
        __threadfence();
        if (t == 0) __hip_atomic_fetch_add(done, 1, __ATOMIC_RELEASE, __HIP_MEMORY_SCOPE_AGENT);
        return;
    }
    // ---- out phase: wait for all producers, then softmax + gather ----
    if (t == 0) {
        while (__hip_atomic_load(done, __ATOMIC_RELAXED, __HIP_MEMORY_SCOPE_AGENT) < DONE_TARGET)
            __builtin_amdgcn_s_sleep(8);
        (void)__hip_atomic_load(done, __ATOMIC_ACQUIRE, __HIP_MEMORY_SCOPE_AGENT);
    }
    __syncthreads();
    int rid = (bx - NEX - NGEMM - NP) * 4 + (t >> 6);  // one wave per (b,i)
    int K = cur[rid];
    K = K > SLOTS ? SLOTS : K;
    int base = rid * SLOTS;
    int b = rid >> 10;
    float* op = out + (size_t)rid * DD + lane * 8;
    if (K == 0) {
        float4 z4 = {0.f, 0.f, 0.f, 0.f};
        *(float4*)op = z4;
        *(float4*)(op + 4) = z4;
        return;
    }
    float p1row = p1[rid];
    int de = (lane < K) ? sDst[base + lane] : -1;
    float ae = (lane < K) ? leaky(p1row + p2[(b << 10) + de]) : 0.f;
    float S = 0.f;
    int c = 0, firstk = 64;
    for (int k = 0; k < K; k++) {
        int dk = __shfl(de, k);
        float ak = __shfl(ae, k);
        bool mt = (lane < K) && (dk == de);
        if (mt) {
            S += ak;
            c++;
            if (k < firstk) firstk = k;
        }
    }
    float logit = (lane < K) ? (S + (float)(c - 1) * 1e9f) : -INFINITY;
    float M = wave_max(logit);
    float contrib = (lane < K && firstk == lane) ? __expf(logit - M) : 0.f;
    float Dsum = wave_sum(contrib);
    float wgt = (lane < K) ? __expf(logit - M) / Dsum : 0.f;
    const short* Zb = Z16 + ((size_t)(b << 10)) * DD;
    float acc[8] = {0.f, 0.f, 0.f, 0.f, 0.f, 0.f, 0.f, 0.f};
#pragma unroll
    for (int k = 0; k < 32; k++) {
        if (k >= K) break;  // wave-uniform break
        int dj = __shfl(de, k);
        float wk = __shfl(wgt, k);
        short8 zv = *(const short8*)(Zb + (size_t)dj * DD + lane * 8);
#pragma unroll
        for (int j = 0; j < 8; j++) acc[j] += wk * b2f(zv[j]);
    }
    for (int k = 32; k < K; k++) {
        int dj = __shfl(de, k);
        float wk = __shfl(wgt, k);
        short8 zv = *(const short8*)(Zb + (size_t)dj * DD + lane * 8);
#pragma unroll
        for (int j = 0; j < 8; j++) acc[j] += wk * b2f(zv[j]);
    }
    float4 o0, o1;
    o0.x = leaky(acc[0]); o0.y = leaky(acc[1]); o0.z = leaky(acc[2]); o0.w = leaky(acc[3]);
    o1.x = leaky(acc[4]); o1.y = leaky(acc[5]); o1.z = leaky(acc[6]); o1.w = leaky(acc[7]);
    *(float4*)op = o0;
    *(float4*)(op + 4) = o1;
}

extern "C" void kernel_launch(void* const* d_in, const int* in_sizes, int n_in,
                              void* d_out, int out_size, void* d_ws, size_t ws_size,
                              hipStream_t stream) {
    const float* nodes = (const float*)d_in[0];
    const float* Cmat = (const float*)d_in[1];
    const float* Nmat = (const float*)d_in[2];
    const float* w = (const float*)d_in[4];
    const float* attn = (const float*)d_in[5];
    float* out = (float*)d_out;

    char* ws = (char*)d_ws;
    size_t off = 0;
    auto alloc = [&](size_t bytes) -> void* {
        void* p = ws + off;
        off += (bytes + 255) & ~(size_t)255;
        return p;
    };
    short* Z16 = (short*)alloc((size_t)BB * NN * DD * 2);              // 4 MB
    __hip_bfloat16* BT = (__hip_bfloat16*)alloc((size_t)FF * DD * 2);  // 0.5 MB
    float* wa1 = (float*)alloc((size_t)FF * 4);
    float* wa2 = (float*)alloc((size_t)FF * 4);
    int* cur = (int*)alloc((size_t)BB * NN * 4);
    int* sDst = (int*)alloc((size_t)BB * NN * SLOTS * 4);  // 1 MB
    float* p1 = (float*)alloc((size_t)BB * NN * 4);
    float* p2 = (float*)alloc((size_t)BB * NN * 4);
    int* done = (int*)alloc(256);

    k_prep<<<193, 256, 0, stream>>>(w, attn, BT, wa1, wa2, cur, done);
    k_mega<<<NEX + NGEMM + NP + NOUT, 256, 0, stream>>>(nodes, BT, wa1, wa2, Cmat, Nmat,
                                                        Z16, p1, p2, cur, sDst, done, out);
}

// Round 7
// 63.635 us; speedup vs baseline: 17.7981x; 17.7981x over previous
//
#include <hip/hip_runtime.h>
#include <hip/hip_bf16.h>
#include <math.h>

#define BB 4
#define EE 8192
#define NN 1024
#define FF 512
#define DD 512
#define ALPHA 0.2f
#define SLOTS 64
#define NEX 8192
#define NGEMM 256
#define NP 1024

typedef __attribute__((ext_vector_type(8))) short short8;
typedef __attribute__((ext_vector_type(4))) float f32x4;

static __device__ __forceinline__ float leaky(float x) { return x > 0.f ? x : ALPHA * x; }

static __device__ __forceinline__ float wave_sum(float v) {
#pragma unroll
    for (int m = 32; m >= 1; m >>= 1) v += __shfl_xor(v, m);
    return v;
}
static __device__ __forceinline__ float wave_max(float v) {
#pragma unroll
    for (int m = 32; m >= 1; m >>= 1) v = fmaxf(v, __shfl_xor(v, m));
    return v;
}
static __device__ __forceinline__ float dot4(float4 a, float4 b) {
    return a.x * b.x + a.y * b.y + a.z * b.z + a.w * b.w;
}
static __device__ __forceinline__ short8 cvt8(float4 a, float4 b) {
    __hip_bfloat16 t[8];
    t[0] = __float2bfloat16(a.x); t[1] = __float2bfloat16(a.y);
    t[2] = __float2bfloat16(a.z); t[3] = __float2bfloat16(a.w);
    t[4] = __float2bfloat16(b.x); t[5] = __float2bfloat16(b.y);
    t[6] = __float2bfloat16(b.z); t[7] = __float2bfloat16(b.w);
    return *(short8*)t;
}
static __device__ __forceinline__ float b2f(short s) {
    unsigned u = ((unsigned)(unsigned short)s) << 16;
    float f;
    __builtin_memcpy(&f, &u, 4);
    return f;
}
static __device__ __forceinline__ short f2b(float f) {
    __hip_bfloat16 h = __float2bfloat16(f);
    short s;
    __builtin_memcpy(&s, &h, 2);
    return s;
}
// locate nonzero within a 3-chunk (768-elem) window; -1 if absent (wave-uniform result)
static __device__ __forceinline__ int find3(uint4 a, uint4 b, uint4 c, int lane) {
    unsigned na = a.x | a.y | a.z | a.w;
    unsigned nb = b.x | b.y | b.z | b.w;
    unsigned nc = c.x | c.y | c.z | c.w;
    int il = -1;
    if (na) il = lane * 4 + (a.x ? 0 : (a.y ? 1 : (a.z ? 2 : 3)));
    else if (nb) il = 256 + lane * 4 + (b.x ? 0 : (b.y ? 1 : (b.z ? 2 : 3)));
    else if (nc) il = 512 + lane * 4 + (c.x ? 0 : (c.y ? 1 : (c.z ? 2 : 3)));
    unsigned long long m = __ballot(il >= 0);
    if (!m) return -1;
    return __shfl(il, (int)__ffsll(m) - 1);
}
// locate within a single 256-elem chunk; -1 if absent (wave-uniform result)
static __device__ __forceinline__ int find1(uint4 v, int lane) {
    unsigned nz = v.x | v.y | v.z | v.w;
    unsigned long long m = __ballot(nz != 0u);
    if (!m) return -1;
    int il = lane * 4 + (v.x ? 0 : (v.y ? 1 : (v.z ? 2 : 3)));
    return __shfl(il, (int)__ffsll(m) - 1);
}

// ---------------- K1 (prep): w transpose->bf16, wa = w@a, zero cur ----------------
__global__ __launch_bounds__(256) void k_prep(const float* __restrict__ w,
                                              const float* __restrict__ attn,
                                              __hip_bfloat16* __restrict__ BT,
                                              float* __restrict__ wa1, float* __restrict__ wa2,
                                              int* __restrict__ cur) {
    int bx = blockIdx.x;
    if (bx < 64) {
        __shared__ float tile[64][65];
        int tk = bx >> 3, tn = bx & 7;
        int k0 = tk * 64, n0 = tn * 64;
#pragma unroll
        for (int it = 0; it < 16; ++it) {
            int id = it * 256 + threadIdx.x;
            int r = id >> 6, c = id & 63;
            tile[r][c] = w[(size_t)(k0 + r) * DD + n0 + c];
        }
        __syncthreads();
#pragma unroll
        for (int it = 0; it < 16; ++it) {
            int id = it * 256 + threadIdx.x;
            int r = id >> 6, c = id & 63;
            BT[(size_t)(n0 + r) * FF + k0 + c] = __float2bfloat16(tile[c][r]);
        }
        return;
    }
    if (bx < 192) {
        int f = (bx - 64) * 4 + (threadIdx.x >> 6);
        int lane = threadIdx.x & 63;
        const float4* wr = (const float4*)(w + (size_t)f * DD);
        const float4* a1p = (const float4*)attn;
        const float4* a2p = (const float4*)(attn + DD);
        float4 wv0 = wr[lane], wv1 = wr[64 + lane];
        float s1 = dot4(wv0, a1p[lane]) + dot4(wv1, a1p[64 + lane]);
        float s2 = dot4(wv0, a2p[lane]) + dot4(wv1, a2p[64 + lane]);
        s1 = wave_sum(s1);
        s2 = wave_sum(s2);
        if (lane == 0) {
            wa1[f] = s1;
            wa2[f] = s2;
        }
        return;
    }
    int4* cp = (int4*)cur;
    int4 z4 = {0, 0, 0, 0};
#pragma unroll
    for (int j = 0; j < 4; j++) cp[threadIdx.x * 4 + j] = z4;
}

// ---------------- K2 (mega): extract first, then gemm, then p-rows ----------------
#define BM 128
#define BN 64
#define BK 32
__global__ __launch_bounds__(256) void k_mega(const float* __restrict__ nodes,
                                              const __hip_bfloat16* __restrict__ BTbf,
                                              const float* __restrict__ wa1,
                                              const float* __restrict__ wa2,
                                              const float* __restrict__ C,
                                              const float* __restrict__ Nm,
                                              short* __restrict__ Z16,
                                              float* __restrict__ p1, float* __restrict__ p2,
                                              int* __restrict__ cur, int* __restrict__ sDst) {
    __shared__ short As[BM][BK + 8];
    __shared__ short Bs[BN][BK + 8];
    int bx = blockIdx.x;
    int t = threadIdx.x;
    int lane = t & 63;
    if (bx < NEX) {
        // ---- extract + scatter: one wave per edge; 3-chunk window then chunk 3 ----
        int widx = bx * 4 + (t >> 6);
        const uint4* rc = (const uint4*)(C + (size_t)widx * NN);
        const uint4* rn = (const uint4*)(Nm + (size_t)widx * NN);
        uint4 a0 = rc[lane], a1 = rc[64 + lane], a2 = rc[128 + lane];
        uint4 b0 = rn[lane], b1 = rn[64 + lane], b2 = rn[128 + lane];
        int s = find3(a0, a1, a2, lane);
        int d = find3(b0, b1, b2, lane);
        if (s < 0 || d < 0) {
            uint4 va, vb;
            if (s < 0) va = rc[192 + lane];
            if (d < 0) vb = rn[192 + lane];
            if (s < 0) {
                int r = find1(va, lane);
                if (r >= 0) s = 768 + r;
            }
            if (d < 0) {
                int r = find1(vb, lane);
                if (r >= 0) d = 768 + r;
            }
        }
        if (lane == 0) {
            int b = widx >> 13;  // EE = 8192
            int row = b * NN + s;
            int pos = atomicAdd(&cur[row], 1);
            if (pos < SLOTS) sDst[row * SLOTS + pos] = d;
        }
        return;
    }
    if (bx < NEX + NGEMM) {
        // ---- GEMM: Z16 = bf16(nodes) @ BT^T ----
        int gb = bx - NEX;
        int m0 = (gb & 31) * BM;
        int n0 = (gb >> 5) * BN;
        int wid = t >> 6;
        int wm = wid & 1, wn = wid >> 1;
        f32x4 acc[4][2] = {};
        const short* Bg = (const short*)BTbf;
        for (int k0 = 0; k0 < FF; k0 += BK) {
#pragma unroll
            for (int s = 0; s < 2; s++) {
                int cid = t + s * 256;
                int r = cid >> 2, cc = cid & 3;
                const float4* ap = (const float4*)&nodes[(size_t)(m0 + r) * FF + k0 + cc * 8];
                *(short8*)&As[r][cc * 8] = cvt8(ap[0], ap[1]);
            }
            {
                int r = t >> 2, cc = t & 3;
                *(short8*)&Bs[r][cc * 8] = *(const short8*)&Bg[(size_t)(n0 + r) * FF + k0 + cc * 8];
            }
            __syncthreads();
            short8 af[4];
            short8 bf[2];
#pragma unroll
            for (int m = 0; m < 4; m++)
                af[m] = *(const short8*)&As[wm * 64 + m * 16 + (lane & 15)][(lane >> 4) * 8];
#pragma unroll
            for (int n = 0; n < 2; n++)
                bf[n] = *(const short8*)&Bs[wn * 32 + n * 16 + (lane & 15)][(lane >> 4) * 8];
#pragma unroll
            for (int m = 0; m < 4; m++)
#pragma unroll
                for (int n = 0; n < 2; n++)
                    acc[m][n] = __builtin_amdgcn_mfma_f32_16x16x32_bf16(af[m], bf[n], acc[m][n], 0, 0, 0);
            __syncthreads();
        }
#pragma unroll
        for (int m = 0; m < 4; m++)
#pragma unroll
            for (int n = 0; n < 2; n++)
#pragma unroll
                for (int r = 0; r < 4; r++) {
                    int row = m0 + wm * 64 + m * 16 + (lane >> 4) * 4 + r;
                    int col = n0 + wn * 32 + n * 16 + (lane & 15);
                    Z16[(size_t)row * DD + col] = f2b(acc[m][n][r]);
                }
        return;
    }
    // ---- p1/p2 = nodes @ wa1/wa2 (fp32), one wave per row ----
    int rid = (bx - NEX - NGEMM) * 4 + (t >> 6);
    const float4* nr = (const float4*)(nodes + (size_t)rid * FF);
    const float4* w1p = (const float4*)wa1;
    const float4* w2p = (const float4*)wa2;
    float4 v0 = nr[lane], v1 = nr[64 + lane];
    float s1 = dot4(v0, w1p[lane]) + dot4(v1, w1p[64 + lane]);
    float s2 = dot4(v0, w2p[lane]) + dot4(v1, w2p[64 + lane]);
    s1 = wave_sum(s1);
    s2 = wave_sum(s2);
    if (lane == 0) {
        p1[rid] = s1;
        p2[rid] = s2;
    }
}

// ---------------- K3: per-row softmax (exact keras-mask emulation) + output ----------------
__global__ __launch_bounds__(256) void k_out(const int* __restrict__ cur,
                                             const int* __restrict__ sDst,
                                             const float* __restrict__ p1,
                                             const float* __restrict__ p2,
                                             const short* __restrict__ Z16,
                                             float* __restrict__ out) {
    int rid = (blockIdx.x * 256 + threadIdx.x) >> 6;  // one wave per (b,i)
    int lane = threadIdx.x & 63;
    if (rid >= BB * NN) return;
    int K = cur[rid];
    K = K > SLOTS ? SLOTS : K;
    int base = rid * SLOTS;
    int b = rid >> 10;
    float* op = out + (size_t)rid * DD + lane * 8;
    if (K == 0) {
        float4 z4 = {0.f, 0.f, 0.f, 0.f};
        *(float4*)op = z4;
        *(float4*)(op + 4) = z4;
        return;
    }
    float p1row = p1[rid];
    int de = (lane < K) ? sDst[base + lane] : -1;
    float ae = (lane < K) ? leaky(p1row + p2[(b << 10) + de]) : 0.f;
    float S = 0.f;
    int c = 0, firstk = 64;
    for (int k = 0; k < K; k++) {
        int dk = __shfl(de, k);
        float ak = __shfl(ae, k);
        bool mt = (lane < K) && (dk == de);
        if (mt) {
            S += ak;
            c++;
            if (k < firstk) firstk = k;
        }
    }
    float logit = (lane < K) ? (S + (float)(c - 1) * 1e9f) : -INFINITY;
    float M = wave_max(logit);
    float contrib = (lane < K && firstk == lane) ? __expf(logit - M) : 0.f;
    float Dsum = wave_sum(contrib);
    float wgt = (lane < K) ? __expf(logit - M) / Dsum : 0.f;
    const short* Zb = Z16 + ((size_t)(b << 10)) * DD;
    float acc[8] = {0.f, 0.f, 0.f, 0.f, 0.f, 0.f, 0.f, 0.f};
#pragma unroll
    for (int k = 0; k < 32; k++) {
        if (k >= K) break;  // wave-uniform break
        int dj = __shfl(de, k);
        float wk = __shfl(wgt, k);
        short8 zv = *(const short8*)(Zb + (size_t)dj * DD + lane * 8);
#pragma unroll
        for (int j = 0; j < 8; j++) acc[j] += wk * b2f(zv[j]);
    }
    for (int k = 32; k < K; k++) {
        int dj = __shfl(de, k);
        float wk = __shfl(wgt, k);
        short8 zv = *(const short8*)(Zb + (size_t)dj * DD + lane * 8);
#pragma unroll
        for (int j = 0; j < 8; j++) acc[j] += wk * b2f(zv[j]);
    }
    float4 o0, o1;
    o0.x = leaky(acc[0]); o0.y = leaky(acc[1]); o0.z = leaky(acc[2]); o0.w = leaky(acc[3]);
    o1.x = leaky(acc[4]); o1.y = leaky(acc[5]); o1.z = leaky(acc[6]); o1.w = leaky(acc[7]);
    *(float4*)op = o0;
    *(float4*)(op + 4) = o1;
}

extern "C" void kernel_launch(void* const* d_in, const int* in_sizes, int n_in,
                              void* d_out, int out_size, void* d_ws, size_t ws_size,
                              hipStream_t stream) {
    const float* nodes = (const float*)d_in[0];
    const float* Cmat = (const float*)d_in[1];
    const float* Nmat = (const float*)d_in[2];
    const float* w = (const float*)d_in[4];
    const float* attn = (const float*)d_in[5];
    float* out = (float*)d_out;

    char* ws = (char*)d_ws;
    size_t off = 0;
    auto alloc = [&](size_t bytes) -> void* {
        void* p = ws + off;
        off += (bytes + 255) & ~(size_t)255;
        return p;
    };
    short* Z16 = (short*)alloc((size_t)BB * NN * DD * 2);              // 4 MB
    __hip_bfloat16* BT = (__hip_bfloat16*)alloc((size_t)FF * DD * 2);  // 0.5 MB
    float* wa1 = (float*)alloc((size_t)FF * 4);
    float* wa2 = (float*)alloc((size_t)FF * 4);
    int* cur = (int*)alloc((size_t)BB * NN * 4);
    int* sDst = (int*)alloc((size_t)BB * NN * SLOTS * 4);  // 1 MB
    float* p1 = (float*)alloc((size_t)BB * NN * 4);
    float* p2 = (float*)alloc((size_t)BB * NN * 4);

    k_prep<<<193, 256, 0, stream>>>(w, attn, BT, wa1, wa2, cur);
    k_mega<<<NEX + NGEMM + NP, 256, 0, stream>>>(nodes, BT, wa1, wa2, Cmat, Nmat,
                                                 Z16, p1, p2, cur, sDst);
    k_out<<<1024, 256, 0, stream>>>(cur, sDst, p1, p2, Z16, out);
}

// Round 8
// 53.361 us; speedup vs baseline: 21.2249x; 1.1925x over previous
//
#include <hip/hip_runtime.h>
#include <hip/hip_bf16.h>
#include <math.h>

#define BB 4
#define EE 8192
#define NN 1024
#define FF 512
#define DD 512
#define ALPHA 0.2f
#define SLOTS 64
#define NGEMM 256
#define NEX 4096   // 4 waves/block, 2 edges/wave -> 32768 edges
#define NP 1024

typedef __attribute__((ext_vector_type(8))) short short8;
typedef __attribute__((ext_vector_type(4))) float f32x4;

static __device__ __forceinline__ float leaky(float x) { return x > 0.f ? x : ALPHA * x; }

static __device__ __forceinline__ float wave_sum(float v) {
#pragma unroll
    for (int m = 32; m >= 1; m >>= 1) v += __shfl_xor(v, m);
    return v;
}
static __device__ __forceinline__ float wave_max(float v) {
#pragma unroll
    for (int m = 32; m >= 1; m >>= 1) v = fmaxf(v, __shfl_xor(v, m));
    return v;
}
static __device__ __forceinline__ float dot4(float4 a, float4 b) {
    return a.x * b.x + a.y * b.y + a.z * b.z + a.w * b.w;
}
static __device__ __forceinline__ short8 cvt8(float4 a, float4 b) {
    __hip_bfloat16 t[8];
    t[0] = __float2bfloat16(a.x); t[1] = __float2bfloat16(a.y);
    t[2] = __float2bfloat16(a.z); t[3] = __float2bfloat16(a.w);
    t[4] = __float2bfloat16(b.x); t[5] = __float2bfloat16(b.y);
    t[6] = __float2bfloat16(b.z); t[7] = __float2bfloat16(b.w);
    return *(short8*)t;
}
static __device__ __forceinline__ float b2f(short s) {
    unsigned u = ((unsigned)(unsigned short)s) << 16;
    float f;
    __builtin_memcpy(&f, &u, 4);
    return f;
}
static __device__ __forceinline__ short f2b(float f) {
    __hip_bfloat16 h = __float2bfloat16(f);
    short s;
    __builtin_memcpy(&s, &h, 2);
    return s;
}
// locate the single nonzero within a 2-chunk (512-elem) window; -1 if absent
static __device__ __forceinline__ int find2(uint4 a, uint4 b, int lane) {
    unsigned za = a.x | a.y | a.z | a.w, zb = b.x | b.y | b.z | b.w;
    unsigned long long m = __ballot((za | zb) != 0u);
    if (!m) return -1;
    int il = za ? (lane * 4 + (a.x ? 0 : (a.y ? 1 : (a.z ? 2 : 3))))
                : (256 + lane * 4 + (b.x ? 0 : (b.y ? 1 : (b.z ? 2 : 3))));
    return __shfl(il, (int)__ffsll(m) - 1);
}
// locate within a single 256-elem chunk; -1 if absent
static __device__ __forceinline__ int find1(uint4 v, int lane) {
    unsigned nz = v.x | v.y | v.z | v.w;
    unsigned long long m = __ballot(nz != 0u);
    if (!m) return -1;
    int il = lane * 4 + (v.x ? 0 : (v.y ? 1 : (v.z ? 2 : 3)));
    return __shfl(il, (int)__ffsll(m) - 1);
}

// ---------------- K1 (prep): w transpose->bf16, wa = w@a, zero cur ----------------
__global__ __launch_bounds__(256) void k_prep(const float* __restrict__ w,
                                              const float* __restrict__ attn,
                                              __hip_bfloat16* __restrict__ BT,
                                              float* __restrict__ wa1, float* __restrict__ wa2,
                                              int* __restrict__ cur) {
    int bx = blockIdx.x;
    if (bx < 64) {
        __shared__ float tile[64][65];
        int tk = bx >> 3, tn = bx & 7;
        int k0 = tk * 64, n0 = tn * 64;
#pragma unroll
        for (int it = 0; it < 16; ++it) {
            int id = it * 256 + threadIdx.x;
            int r = id >> 6, c = id & 63;
            tile[r][c] = w[(size_t)(k0 + r) * DD + n0 + c];
        }
        __syncthreads();
#pragma unroll
        for (int it = 0; it < 16; ++it) {
            int id = it * 256 + threadIdx.x;
            int r = id >> 6, c = id & 63;
            BT[(size_t)(n0 + r) * FF + k0 + c] = __float2bfloat16(tile[c][r]);
        }
        return;
    }
    if (bx < 192) {
        int f = (bx - 64) * 4 + (threadIdx.x >> 6);
        int lane = threadIdx.x & 63;
        const float4* wr = (const float4*)(w + (size_t)f * DD);
        const float4* a1p = (const float4*)attn;
        const float4* a2p = (const float4*)(attn + DD);
        float4 wv0 = wr[lane], wv1 = wr[64 + lane];
        float s1 = dot4(wv0, a1p[lane]) + dot4(wv1, a1p[64 + lane]);
        float s2 = dot4(wv0, a2p[lane]) + dot4(wv1, a2p[64 + lane]);
        s1 = wave_sum(s1);
        s2 = wave_sum(s2);
        if (lane == 0) {
            wa1[f] = s1;
            wa2[f] = s2;
        }
        return;
    }
    int4* cp = (int4*)cur;
    int4 z4 = {0, 0, 0, 0};
#pragma unroll
    for (int j = 0; j < 4; j++) cp[threadIdx.x * 4 + j] = z4;
}

// ---------------- K2 (mega): gemm, then dual-edge extract, then p-rows ----------------
#define BM 128
#define BN 64
#define BK 32
__global__ __launch_bounds__(256) void k_mega(const float* __restrict__ nodes,
                                              const __hip_bfloat16* __restrict__ BTbf,
                                              const float* __restrict__ wa1,
                                              const float* __restrict__ wa2,
                                              const float* __restrict__ C,
                                              const float* __restrict__ Nm,
                                              short* __restrict__ Z16,
                                              float* __restrict__ p1, float* __restrict__ p2,
                                              int* __restrict__ cur, int* __restrict__ sDst) {
    __shared__ short As[BM][BK + 8];
    __shared__ short Bs[BN][BK + 8];
    int bx = blockIdx.x;
    int t = threadIdx.x;
    int lane = t & 63;
    if (bx < NGEMM) {
        // ---- GEMM: Z16 = bf16(nodes) @ BT^T ----
        int m0 = (bx & 31) * BM;
        int n0 = (bx >> 5) * BN;
        int wid = t >> 6;
        int wm = wid & 1, wn = wid >> 1;
        f32x4 acc[4][2] = {};
        const short* Bg = (const short*)BTbf;
        for (int k0 = 0; k0 < FF; k0 += BK) {
#pragma unroll
            for (int s = 0; s < 2; s++) {
                int cid = t + s * 256;
                int r = cid >> 2, cc = cid & 3;
                const float4* ap = (const float4*)&nodes[(size_t)(m0 + r) * FF + k0 + cc * 8];
                *(short8*)&As[r][cc * 8] = cvt8(ap[0], ap[1]);
            }
            {
                int r = t >> 2, cc = t & 3;
                *(short8*)&Bs[r][cc * 8] = *(const short8*)&Bg[(size_t)(n0 + r) * FF + k0 + cc * 8];
            }
            __syncthreads();
            short8 af[4];
            short8 bf[2];
#pragma unroll
            for (int m = 0; m < 4; m++)
                af[m] = *(const short8*)&As[wm * 64 + m * 16 + (lane & 15)][(lane >> 4) * 8];
#pragma unroll
            for (int n = 0; n < 2; n++)
                bf[n] = *(const short8*)&Bs[wn * 32 + n * 16 + (lane & 15)][(lane >> 4) * 8];
#pragma unroll
            for (int m = 0; m < 4; m++)
#pragma unroll
                for (int n = 0; n < 2; n++)
                    acc[m][n] = __builtin_amdgcn_mfma_f32_16x16x32_bf16(af[m], bf[n], acc[m][n], 0, 0, 0);
            __syncthreads();
        }
#pragma unroll
        for (int m = 0; m < 4; m++)
#pragma unroll
            for (int n = 0; n < 2; n++)
#pragma unroll
                for (int r = 0; r < 4; r++) {
                    int row = m0 + wm * 64 + m * 16 + (lane >> 4) * 4 + r;
                    int col = n0 + wn * 32 + n * 16 + (lane & 15);
                    Z16[(size_t)row * DD + col] = f2b(acc[m][n][r]);
                }
        return;
    }
    if (bx < NGEMM + NEX) {
        // ---- extract + scatter: TWO edges per wave, all 8 window loads issued upfront ----
        int eA = (bx - NGEMM) * 8 + (t >> 6) * 2;  // even edge
        int eB = eA + 1;
        const uint4* rcA = (const uint4*)(C + (size_t)eA * NN);
        const uint4* rnA = (const uint4*)(Nm + (size_t)eA * NN);
        const uint4* rcB = (const uint4*)(C + (size_t)eB * NN);
        const uint4* rnB = (const uint4*)(Nm + (size_t)eB * NN);
        uint4 aA0 = rcA[lane], aA1 = rcA[64 + lane];
        uint4 bA0 = rnA[lane], bA1 = rnA[64 + lane];
        uint4 aB0 = rcB[lane], aB1 = rcB[64 + lane];
        uint4 bB0 = rnB[lane], bB1 = rnB[64 + lane];
        int sA = find2(aA0, aA1, lane);
        int dA = find2(bA0, bA1, lane);
        int sB = find2(aB0, aB1, lane);
        int dB = find2(bB0, bB1, lane);
#pragma unroll 1
        for (int c = 2; c < 4 && ((sA < 0) | (dA < 0) | (sB < 0) | (dB < 0)); ++c) {
            uint4 vaA, vbA, vaB, vbB;
            bool nsA = sA < 0, ndA = dA < 0, nsB = sB < 0, ndB = dB < 0;
            if (nsA) vaA = rcA[c * 64 + lane];
            if (ndA) vbA = rnA[c * 64 + lane];
            if (nsB) vaB = rcB[c * 64 + lane];
            if (ndB) vbB = rnB[c * 64 + lane];
            if (nsA) {
                int r = find1(vaA, lane);
                if (r >= 0) sA = c * 256 + r;
            }
            if (ndA) {
                int r = find1(vbA, lane);
                if (r >= 0) dA = c * 256 + r;
            }
            if (nsB) {
                int r = find1(vaB, lane);
                if (r >= 0) sB = c * 256 + r;
            }
            if (ndB) {
                int r = find1(vbB, lane);
                if (r >= 0) dB = c * 256 + r;
            }
        }
        if (lane == 0) {
            int b = eA >> 13;  // pair never straddles the batch boundary
            int rowA = b * NN + sA;
            int posA = atomicAdd(&cur[rowA], 1);
            if (posA < SLOTS) sDst[rowA * SLOTS + posA] = dA;
            int rowB = b * NN + sB;
            int posB = atomicAdd(&cur[rowB], 1);
            if (posB < SLOTS) sDst[rowB * SLOTS + posB] = dB;
        }
        return;
    }
    // ---- p1/p2 = nodes @ wa1/wa2 (fp32), one wave per row ----
    int rid = (bx - NGEMM - NEX) * 4 + (t >> 6);
    const float4* nr = (const float4*)(nodes + (size_t)rid * FF);
    const float4* w1p = (const float4*)wa1;
    const float4* w2p = (const float4*)wa2;
    float4 v0 = nr[lane], v1 = nr[64 + lane];
    float s1 = dot4(v0, w1p[lane]) + dot4(v1, w1p[64 + lane]);
    float s2 = dot4(v0, w2p[lane]) + dot4(v1, w2p[64 + lane]);
    s1 = wave_sum(s1);
    s2 = wave_sum(s2);
    if (lane == 0) {
        p1[rid] = s1;
        p2[rid] = s2;
    }
}

// ---------------- K3: per-row softmax (exact keras-mask emulation) + output ----------------
__global__ __launch_bounds__(256) void k_out(const int* __restrict__ cur,
                                             const int* __restrict__ sDst,
                                             const float* __restrict__ p1,
                                             const float* __restrict__ p2,
                                             const short* __restrict__ Z16,
                                             float* __restrict__ out) {
    int rid = (blockIdx.x * 256 + threadIdx.x) >> 6;  // one wave per (b,i)
    int lane = threadIdx.x & 63;
    if (rid >= BB * NN) return;
    int K = cur[rid];
    K = K > SLOTS ? SLOTS : K;
    int base = rid * SLOTS;
    int b = rid >> 10;
    float* op = out + (size_t)rid * DD + lane * 8;
    if (K == 0) {
        float4 z4 = {0.f, 0.f, 0.f, 0.f};
        *(float4*)op = z4;
        *(float4*)(op + 4) = z4;
        return;
    }
    float p1row = p1[rid];
    int de = (lane < K) ? sDst[base + lane] : -1;
    float ae = (lane < K) ? leaky(p1row + p2[(b << 10) + de]) : 0.f;
    float S = 0.f;
    int c = 0, firstk = 64;
    for (int k = 0; k < K; k++) {
        int dk = __shfl(de, k);
        float ak = __shfl(ae, k);
        bool mt = (lane < K) && (dk == de);
        if (mt) {
            S += ak;
            c++;
            if (k < firstk) firstk = k;
        }
    }
    float logit = (lane < K) ? (S + (float)(c - 1) * 1e9f) : -INFINITY;
    float M = wave_max(logit);
    float contrib = (lane < K && firstk == lane) ? __expf(logit - M) : 0.f;
    float Dsum = wave_sum(contrib);
    float wgt = (lane < K) ? __expf(logit - M) / Dsum : 0.f;
    const short* Zb = Z16 + ((size_t)(b << 10)) * DD;
    float acc[8] = {0.f, 0.f, 0.f, 0.f, 0.f, 0.f, 0.f, 0.f};
#pragma unroll
    for (int k = 0; k < 32; k++) {
        if (k >= K) break;  // wave-uniform break
        int dj = __shfl(de, k);
        float wk = __shfl(wgt, k);
        short8 zv = *(const short8*)(Zb + (size_t)dj * DD + lane * 8);
#pragma unroll
        for (int j = 0; j < 8; j++) acc[j] += wk * b2f(zv[j]);
    }
    for (int k = 32; k < K; k++) {
        int dj = __shfl(de, k);
        float wk = __shfl(wgt, k);
        short8 zv = *(const short8*)(Zb + (size_t)dj * DD + lane * 8);
#pragma unroll
        for (int j = 0; j < 8; j++) acc[j] += wk * b2f(zv[j]);
    }
    float4 o0, o1;
    o0.x = leaky(acc[0]); o0.y = leaky(acc[1]); o0.z = leaky(acc[2]); o0.w = leaky(acc[3]);
    o1.x = leaky(acc[4]); o1.y = leaky(acc[5]); o1.z = leaky(acc[6]); o1.w = leaky(acc[7]);
    *(float4*)op = o0;
    *(float4*)(op + 4) = o1;
}

extern "C" void kernel_launch(void* const* d_in, const int* in_sizes, int n_in,
                              void* d_out, int out_size, void* d_ws, size_t ws_size,
                              hipStream_t stream) {
    const float* nodes = (const float*)d_in[0];
    const float* Cmat = (const float*)d_in[1];
    const float* Nmat = (const float*)d_in[2];
    const float* w = (const float*)d_in[4];
    const float* attn = (const float*)d_in[5];
    float* out = (float*)d_out;

    char* ws = (char*)d_ws;
    size_t off = 0;
    auto alloc = [&](size_t bytes) -> void* {
        void* p = ws + off;
        off += (bytes + 255) & ~(size_t)255;
        return p;
    };
    short* Z16 = (short*)alloc((size_t)BB * NN * DD * 2);              // 4 MB
    __hip_bfloat16* BT = (__hip_bfloat16*)alloc((size_t)FF * DD * 2);  // 0.5 MB
    float* wa1 = (float*)alloc((size_t)FF * 4);
    float* wa2 = (float*)alloc((size_t)FF * 4);
    int* cur = (int*)alloc((size_t)BB * NN * 4);
    int* sDst = (int*)alloc((size_t)BB * NN * SLOTS * 4);  // 1 MB
    float* p1 = (float*)alloc((size_t)BB * NN * 4);
    float* p2 = (float*)alloc((size_t)BB * NN * 4);

    k_prep<<<193, 256, 0, stream>>>(w, attn, BT, wa1, wa2, cur);
    k_mega<<<NGEMM + NEX + NP, 256, 0, stream>>>(nodes, BT, wa1, wa2, Cmat, Nmat,
                                                 Z16, p1, p2, cur, sDst);
    k_out<<<1024, 256, 0, stream>>>(cur, sDst, p1, p2, Z16, out);
}